// Round 8
// baseline (639.995 us; speedup 1.0000x reference)
//
#include <hip/hip_runtime.h>
#include <math.h>

// Problem constants (from reference): T=128, B=2048, D=256, ALPHA=0.5, VTH=1.0
#define TT 128
#define BB 2048
#define DDIM 256
#define BD (BB * DDIM)

// GL coefficients c[j] = prod_{i=1..j} (1 - (1+alpha)/i), computed in f64 then
// cast to f32 — exactly mirrors _gl_coeffs (float64 cumprod -> float32 cast).
struct Coeffs {
    float c[TT + 1];
};
static constexpr Coeffs make_coeffs() {
    Coeffs r{};
    r.c[0] = 1.0f;
    double cur = 1.0;
    for (int j = 1; j <= TT; ++j) {
        cur *= (1.0 - 1.5 / (double)j);  // (1+alpha) = 1.5
        r.c[j] = (float)cur;
    }
    return r;
}
static constexpr Coeffs CO = make_coeffs();

// One thread per (b,d) sequence — 16x16 register-tiled triangular convolution
// with EXPLICIT register-class control.
//
// R1-R7 established: (a) the allocator either parks y[128] in AGPRs and pays
// one shuttle per FMA (R1-R6: 19K VALU instrs/wave, 2x floor) or spills y to
// scratch (R7: +600MB HBM traffic); (b) budget attributes are floors/caps,
// never targets, so they produced identical binaries; (c) R7's tiled
// iteration order is bit-exact (absmax unchanged).
//
// R8 takes allocation out of the heuristic's hands:
//  - amdgpu_waves_per_eu(2,2): MAX=2 clamps the occupancy target -> 256-reg
//    budget, removing the incentive to spill at all.
//  - y[] lives in AGPRs by construction: defined only via v_accvgpr_write,
//    read only via v_accvgpr_read (16-wide tile copies -> 576 shuttle ops
//    total instead of 8128).
//  - coefficient bands pinned to SGPRs per tile (volatile scoping stops CSE
//    from stretching live ranges): s_mov materialization is SALU (parallel
//    pipe), and v_fma with one SGPR source encodes in a single VALU op.
__global__ __attribute__((amdgpu_flat_work_group_size(256, 256),
                          amdgpu_waves_per_eu(2, 2)))
void gl_if_kernel(const float* __restrict__ x, float* __restrict__ sp) {
    const int g = blockIdx.x * 256 + threadIdx.x;  // (b,d) flat index
    float y[TT];  // AGPR-resident history: touched only via accvgpr asm below

#pragma unroll
    for (int K = 0; K < TT / 16; ++K) {
        // x values for this step block (coalesced; issued ahead of the tiles)
        float xv[16];
#pragma unroll
        for (int r = 0; r < 16; ++r) {
            xv[r] = x[g + (size_t)(16 * K + r) * BD];
        }

        float acc[16];
#pragma unroll
        for (int r = 0; r < 16; ++r) acc[r] = 0.0f;

        // Full history tiles I < K: slots 16I..16I+15, coeffs 16(K-I)-15..+15
#pragma unroll
        for (int I = 0; I < K; ++I) {
            // 31-coefficient band for this tile distance -> SGPRs
            float cb[31];
#pragma unroll
            for (int d = 0; d < 31; ++d) {
                cb[d] = CO.c[16 * (K - I) - 15 + d];
                asm volatile("" : "+s"(cb[d]));
            }
            // copy y-tile AGPR -> VGPR once (16 reads amortized over 256 FMAs)
            float yt[16];
#pragma unroll
            for (int s = 0; s < 16; ++s) {
                asm volatile("v_accvgpr_read_b32 %0, %1"
                             : "=v"(yt[s])
                             : "a"(y[16 * I + s]));
            }
            // dense 16x16 FMA tile; slot-ascending order per step (bit-exact,
            // validated by R7)
#pragma unroll
            for (int r = 0; r < 16; ++r) {
#pragma unroll
                for (int s = 0; s < 16; ++s) {
                    acc[r] = fmaf(cb[r - s + 15], yt[s], acc[r]);
                }
            }
        }

        // Diagonal tile + spike/reset (sequential part), coeffs c[1..15]
        float cd[16];
#pragma unroll
        for (int d = 1; d < 16; ++d) {
            cd[d] = CO.c[d];
            asm volatile("" : "+s"(cd[d]));
        }
        float yn[16];
#pragma unroll
        for (int r = 0; r < 16; ++r) {
            float a = acc[r];
#pragma unroll
            for (int s = 0; s < r; ++s) {
                a = fmaf(cd[r - s], yn[s], a);  // newest dep last in the chain
            }
            const float men0 = xv[r] - a;
            const float spike = (men0 > 1.0f) ? 1.0f : 0.0f;
            yn[r] = men0 - spike;  // VTH = 1.0
            sp[g + (size_t)(16 * K + r) * BD] = spike;
        }
        // commit the new tile to AGPR history
#pragma unroll
        for (int r = 0; r < 16; ++r) {
            asm volatile("v_accvgpr_write_b32 %0, %1"
                         : "=a"(y[16 * K + r])
                         : "v"(yn[r]));
        }
    }
}

// Lorentz expmap: per row b, vv = -v0^2 + sum_{d>=1} vd^2; s = sqrt(max(vv,eps));
// out = cosh(s)*z + (sinh(s)/s)*v.  One block per row, one thread per d.
__global__ __launch_bounds__(256) void expmap_kernel(const float* __restrict__ v,
                                                     const float* __restrict__ z,
                                                     float* __restrict__ out) {
    const int b = blockIdx.x;
    const int d = threadIdx.x;
    const size_t idx = (size_t)b * DDIM + d;
    const float vd = v[idx];

    float term = vd * vd;
    if (d == 0) term = -term;

    // reduce across the 256-thread block (4 waves of 64)
    float sum = term;
#pragma unroll
    for (int off = 32; off > 0; off >>= 1) sum += __shfl_down(sum, off, 64);

    __shared__ float ws[4];
    if ((threadIdx.x & 63) == 0) ws[threadIdx.x >> 6] = sum;
    __syncthreads();
    const float vv = ws[0] + ws[1] + ws[2] + ws[3];

    const float s2 = fmaxf(vv, 1e-6f);
    const float s = sqrtf(s2);
    const float ch = coshf(s);
    const float shs = sinhf(s) / s;

    out[idx] = ch * z[idx] + shs * vd;
}

extern "C" void kernel_launch(void* const* d_in, const int* in_sizes, int n_in,
                              void* d_out, int out_size, void* d_ws, size_t ws_size,
                              hipStream_t stream) {
    const float* x_seq = (const float*)d_in[0];
    const float* v_seq = (const float*)d_in[1];
    const float* z_seq = (const float*)d_in[2];

    float* s_out = (float*)d_out;                       // [T,B,D] spikes
    float* z_out = (float*)d_out + (size_t)TT * BD;     // [B,D] expmap

    gl_if_kernel<<<BD / 256, 256, 0, stream>>>(x_seq, s_out);
    expmap_kernel<<<BB, DDIM, 0, stream>>>(v_seq, z_seq, z_out);
}

// Round 9
// 136.601 us; speedup vs baseline: 4.6851x; 4.6851x over previous
//
#include <hip/hip_runtime.h>
#include <math.h>

// Problem constants (from reference): T=128, B=2048, D=256, ALPHA=0.5, VTH=1.0
#define TT 128
#define BB 2048
#define DDIM 256
#define BD (BB * DDIM)

// GL coefficients c[j] = prod_{i=1..j} (1 - (1+alpha)/i), computed in f64 then
// cast to f32 — exactly mirrors _gl_coeffs (float64 cumprod -> float32 cast).
struct Coeffs {
    float c[TT + 1];
};
static constexpr Coeffs make_coeffs() {
    Coeffs r{};
    r.c[0] = 1.0f;
    double cur = 1.0;
    for (int j = 1; j <= TT; ++j) {
        cur *= (1.0 - 1.5 / (double)j);  // (1+alpha) = 1.5
        r.c[j] = (float)cur;
    }
    return r;
}
static constexpr Coeffs CO = make_coeffs();

// One thread per (b,d) sequence — 16x16 register-tiled triangular convolution,
// ZERO register-class coercion (the R1-R8 lesson).
//
// Cycle accounting across rounds (8 work-waves/SIMD, 2 cyc/instr):
//   R1 monolithic:        19.1K VALU instrs/wave (2.0 per FMA: y[] homed in
//                         AGPRs, one v_accvgpr_read per use)         155 µs
//   R7 tiled + asm pins:  11.7K instrs/wave (tiling DID kill the companion
//                         op) but the opaque "+v" pins pushed y[] to scratch
//                         (+600 MB HBM)                               253 µs
//   R8 explicit a/s asm:  scratch + scheduling walls                  657 µs
// => The tiled ITERATION ORDER is right; every coercion attempt made
//    allocation worse. R9 = R7 structure, pure C. Each y[16I+s] has its 16
//    uses clustered in one 256-FMA window, so live-range splitting reloads
//    it once per tile from its home (AGPR) instead of once per FMA; acc[16]
//    and the tile window have high use density and take arch VGPRs.
//
// Bit-exactness: for every step k the accumulation visits slots i=0..k-2 in
// ascending order with the same fmaf ops as the reference tensordot
// (tiles ascend, s ascends within tile; per-step accumulators independent) —
// empirically confirmed by R6/R7 (absmax identical to R1).
__global__ __launch_bounds__(256) void gl_if_kernel(const float* __restrict__ x,
                                                    float* __restrict__ sp) {
    const int g = blockIdx.x * 256 + threadIdx.x;  // (b,d) flat index
    float y[TT];  // persistent history; AGPR residency expected and fine

#pragma unroll
    for (int K = 0; K < TT / 16; ++K) {
        float acc[16];
#pragma unroll
        for (int r = 0; r < 16; ++r) acc[r] = 0.0f;

        // Full history tiles I < K: slots 16I..16I+15 satisfy i <= k-2 for
        // every step k in this block. 256 FMAs per tile over a 16-element
        // y-window and a 31-coefficient band.
#pragma unroll
        for (int I = 0; I < K; ++I) {
#pragma unroll
            for (int r = 0; r < 16; ++r) {
#pragma unroll
                for (int s = 0; s < 16; ++s) {
                    // step k = 16K+r+1, slot i = 16I+s, coeff j = k-1-i
                    acc[r] = fmaf(CO.c[16 * (K - I) + r - s], y[16 * I + s],
                                  acc[r]);
                }
            }
        }

        // Diagonal tile + spike/reset (the sequential part)
        float yn[16];
#pragma unroll
        for (int r = 0; r < 16; ++r) {
            float a = acc[r];
#pragma unroll
            for (int s = 0; s < r; ++s) {
                a = fmaf(CO.c[r - s], yn[s], a);
            }
            const float xk = x[g + (size_t)(16 * K + r) * BD];
            const float men0 = xk - a;
            const float spike = (men0 > 1.0f) ? 1.0f : 0.0f;
            yn[r] = men0 - spike;  // VTH = 1.0
            sp[g + (size_t)(16 * K + r) * BD] = spike;
        }
#pragma unroll
        for (int r = 0; r < 16; ++r) y[16 * K + r] = yn[r];
    }
}

// Lorentz expmap: per row b, vv = -v0^2 + sum_{d>=1} vd^2; s = sqrt(max(vv,eps));
// out = cosh(s)*z + (sinh(s)/s)*v.  One block per row, one thread per d.
__global__ __launch_bounds__(256) void expmap_kernel(const float* __restrict__ v,
                                                     const float* __restrict__ z,
                                                     float* __restrict__ out) {
    const int b = blockIdx.x;
    const int d = threadIdx.x;
    const size_t idx = (size_t)b * DDIM + d;
    const float vd = v[idx];

    float term = vd * vd;
    if (d == 0) term = -term;

    // reduce across the 256-thread block (4 waves of 64)
    float sum = term;
#pragma unroll
    for (int off = 32; off > 0; off >>= 1) sum += __shfl_down(sum, off, 64);

    __shared__ float ws[4];
    if ((threadIdx.x & 63) == 0) ws[threadIdx.x >> 6] = sum;
    __syncthreads();
    const float vv = ws[0] + ws[1] + ws[2] + ws[3];

    const float s2 = fmaxf(vv, 1e-6f);
    const float s = sqrtf(s2);
    const float ch = coshf(s);
    const float shs = sinhf(s) / s;

    out[idx] = ch * z[idx] + shs * vd;
}

extern "C" void kernel_launch(void* const* d_in, const int* in_sizes, int n_in,
                              void* d_out, int out_size, void* d_ws, size_t ws_size,
                              hipStream_t stream) {
    const float* x_seq = (const float*)d_in[0];
    const float* v_seq = (const float*)d_in[1];
    const float* z_seq = (const float*)d_in[2];

    float* s_out = (float*)d_out;                       // [T,B,D] spikes
    float* z_out = (float*)d_out + (size_t)TT * BD;     // [B,D] expmap

    gl_if_kernel<<<BD / 256, 256, 0, stream>>>(x_seq, s_out);
    expmap_kernel<<<BB, DDIM, 0, stream>>>(v_seq, z_seq, z_out);
}